// Round 2
// 391.754 us; speedup vs baseline: 1.5425x; 1.5425x over previous
//
#include <hip/hip_runtime.h>

// B=8, C=64, N=2048, K=32, H=8, d=8. Inputs FLOAT32; output FLOAT32.
// R10: knn = MFMA gemm (D' in 134MB ws) + VALU select. Gemm now uses an
// EXACT 3-way bf16 split (x = hi+mid+lo, all RNE, Sterbenz-exact residuals)
// with 6 MFMA products -> f32-precision Gram regardless of input grid.
// Epilogue restores the reference's op order ((2G - xx_n) - xx_m).
// R9 failed (absmax 0.48 = a few neighbor flips) from bf16 TRUNCATION of
// inputs + dropped -xx_n term. Old fused knn_kernel kept as ws fallback.

#define NN 2048

typedef __attribute__((ext_vector_type(8))) short bf16x8;
typedef __attribute__((ext_vector_type(4))) float f32x4;

// Exact 3-way bf16 split of an f32 value (hi+mid+lo == x exactly).
__device__ inline void bsplit(float x, short& h, short& m, short& l)
{
    unsigned u  = __float_as_uint(x);
    unsigned hb = (u + 0x7FFFu + ((u >> 16) & 1u)) >> 16;
    float hf = __uint_as_float(hb << 16);
    float r1 = x - hf;                       // exact (Sterbenz)
    unsigned u1 = __float_as_uint(r1);
    unsigned mb = (u1 + 0x7FFFu + ((u1 >> 16) & 1u)) >> 16;
    float mf = __uint_as_float(mb << 16);
    float r2 = r1 - mf;                      // exact; <= 8 significant bits
    unsigned u2 = __float_as_uint(r2);
    unsigned lb = (u2 + 0x7FFFu + ((u2 >> 16) & 1u)) >> 16;
    h = (short)hb; m = (short)mb; l = (short)lb;
}

// ---------------------------------------------------------------- prep ------
// Per 32-point tile: xx = sum x^2; K/V projections (fp32, point-major).
__global__ __launch_bounds__(256) void prep_kernel(
    const float* __restrict__ x, const float* __restrict__ Wk,
    const float* __restrict__ Wv, float* __restrict__ xx,
    float* __restrict__ KT, float* __restrict__ VT)
{
    __shared__ float xs[64][33];
    __shared__ float wks[4096], wvs[4096];
    const int t = threadIdx.x;
    const int b = blockIdx.x >> 6;
    const int n0 = (blockIdx.x & 63) * 32;
    for (int i = 0; i < 16; ++i) {
        int e = t + 256 * i;
        wks[e] = Wk[e];
        wvs[e] = Wv[e];
    }
    for (int i = 0; i < 8; ++i) {
        int e = t + 256 * i;
        xs[e >> 5][e & 31] = x[((size_t)b * 64 + (e >> 5)) * 2048 + n0 + (e & 31)];
    }
    __syncthreads();
    if (t < 32) {
        float s = 0.f;
#pragma unroll
        for (int c = 0; c < 64; ++c) { float v = xs[c][t]; s += v * v; }
        xx[b * 2048 + n0 + t] = s;
    }
    {
        int p = t & 31, g = t >> 5;  // 8 output channels per thread
        float xv[64];
#pragma unroll
        for (int c = 0; c < 64; ++c) xv[c] = xs[c][p];
        size_t base = ((size_t)(b * 2048 + n0 + p)) * 64 + g * 8;
        float ok[8], ov[8];
#pragma unroll
        for (int oi = 0; oi < 8; ++oi) {
            int o = g * 8 + oi;
            float ak = 0.f, av = 0.f;
#pragma unroll
            for (int c = 0; c < 64; ++c) {
                float xc = xv[c];
                ak += wks[o * 64 + c] * xc;
                av += wvs[o * 64 + c] * xc;
            }
            ok[oi] = ak; ov[oi] = av;
        }
        *reinterpret_cast<float4*>(KT + base)     = make_float4(ok[0], ok[1], ok[2], ok[3]);
        *reinterpret_cast<float4*>(KT + base + 4) = make_float4(ok[4], ok[5], ok[6], ok[7]);
        *reinterpret_cast<float4*>(VT + base)     = make_float4(ov[0], ov[1], ov[2], ov[3]);
        *reinterpret_cast<float4*>(VT + base + 4) = make_float4(ov[4], ov[5], ov[6], ov[7]);
    }
}

// ------------------------------------------------------------- knn gemm -----
// D'[b][n][m] = (2*G[n][m] - xx[n]) - xx[m], f32-precision via 3-way bf16
// split and 6 MFMA products (hh, hm, mh, hl, lh, mm); dropped terms <=2^-24.
// Block = 128x128 output tile (4 waves x 32 rows). Grid 2048 = 8 b x 256.
__global__ __launch_bounds__(256) void gemm_kernel(
    const float* __restrict__ x, const float* __restrict__ xx,
    float* __restrict__ Dp)
{
    const int t = threadIdx.x;
    const int lane = t & 63;
    const int w = t >> 6;
    const int b = blockIdx.x >> 8;
    const int tile = blockIdx.x & 255;
    const int r0 = (tile >> 4) * 128 + w * 32;  // wave's first row
    const int c0 = (tile & 15) * 128;           // block col base
    const int rl = lane & 15;                   // row/col within 16-block
    const int kg = (lane >> 4) * 8;             // k-group base (0,8,16,24)

    const float* xb = x + (size_t)b * 64 * 2048;

    f32x4 acc[2][8];
#pragma unroll
    for (int rb = 0; rb < 2; ++rb)
#pragma unroll
        for (int cb = 0; cb < 8; ++cb)
            acc[rb][cb] = (f32x4){0.f, 0.f, 0.f, 0.f};

#pragma unroll
    for (int s = 0; s < 2; ++s) {               // K slices 0..31, 32..63
        const int kb = s * 32 + kg;
        bf16x8 ah[2], am[2], al[2];
#pragma unroll
        for (int rb = 0; rb < 2; ++rb) {
            const int n = r0 + rb * 16 + rl;
#pragma unroll
            for (int j = 0; j < 8; ++j) {
                short h, m, l;
                bsplit(xb[(size_t)(kb + j) * 2048 + n], h, m, l);
                ah[rb][j] = h; am[rb][j] = m; al[rb][j] = l;
            }
        }
#pragma unroll
        for (int cb = 0; cb < 8; ++cb) {
            const int mcol = c0 + cb * 16 + rl;
            bf16x8 bh, bm, bl;
#pragma unroll
            for (int j = 0; j < 8; ++j) {
                short h, m, l;
                bsplit(xb[(size_t)(kb + j) * 2048 + mcol], h, m, l);
                bh[j] = h; bm[j] = m; bl[j] = l;
            }
#pragma unroll
            for (int rb = 0; rb < 2; ++rb) {
                f32x4 a = acc[rb][cb];
                a = __builtin_amdgcn_mfma_f32_16x16x32_bf16(al[rb], bh, a, 0, 0, 0);
                a = __builtin_amdgcn_mfma_f32_16x16x32_bf16(ah[rb], bl, a, 0, 0, 0);
                a = __builtin_amdgcn_mfma_f32_16x16x32_bf16(am[rb], bm, a, 0, 0, 0);
                a = __builtin_amdgcn_mfma_f32_16x16x32_bf16(am[rb], bh, a, 0, 0, 0);
                a = __builtin_amdgcn_mfma_f32_16x16x32_bf16(ah[rb], bm, a, 0, 0, 0);
                a = __builtin_amdgcn_mfma_f32_16x16x32_bf16(ah[rb], bh, a, 0, 0, 0);
                acc[rb][cb] = a;
            }
        }
    }

    // epilogue: C/D layout col=lane&15, row=(lane>>4)*4+reg  [m89-verified]
    const float* xxb = xx + b * 2048;
    const int rg = (lane >> 4) * 4;
#pragma unroll
    for (int cb = 0; cb < 8; ++cb) {
        const int col = c0 + cb * 16 + rl;
        const float xc = xxb[col];
#pragma unroll
        for (int rb = 0; rb < 2; ++rb) {
            const int rbase = r0 + rb * 16 + rg;
#pragma unroll
            for (int e = 0; e < 4; ++e) {
                float v = 2.f * acc[rb][cb][e] - xxb[rbase + e];  // (2G - xx_n)
                v = v - xc;                                       // ... - xx_m
                Dp[((size_t)(b * 2048 + rbase + e)) * 2048 + col] = v;
            }
        }
    }
}

// ------------------------------------------------------------ knn select ----
// Top-32 per row from precomputed D'. 1 row per wave, 4 rows per block.
// Lane holds cols [lane*32, lane*32+32); extraction: masked local argmax ->
// 64-lane butterfly argmax (tie: low index) -> owner marks consumed.
__global__ __launch_bounds__(256) void select_kernel(
    const float* __restrict__ Dp, int* __restrict__ idx)
{
    const int t = threadIdx.x, w = t >> 6, lane = t & 63;
    const int b = blockIdx.x >> 9;
    const int r = (blockIdx.x & 511) * 4 + w;
    const float* row = Dp + ((size_t)(b * 2048 + r)) * 2048;
    float v[32];
#pragma unroll
    for (int q = 0; q < 8; ++q) {
        float4 f = *reinterpret_cast<const float4*>(row + lane * 32 + q * 4);
        v[q * 4 + 0] = f.x; v[q * 4 + 1] = f.y;
        v[q * 4 + 2] = f.z; v[q * 4 + 3] = f.w;
    }
    unsigned mask = 0u;
    int* orow = idx + ((size_t)(b * 2048 + r)) * 32;
    for (int it = 0; it < 32; ++it) {
        float bv = -INFINITY; int bj = 0;
#pragma unroll
        for (int j = 0; j < 32; ++j) {
            bool ok = !((mask >> j) & 1u) && (v[j] > bv);
            bv = ok ? v[j] : bv;
            bj = ok ? j : bj;
        }
        int bi = lane * 32 + bj;
#pragma unroll
        for (int d = 1; d < 64; d <<= 1) {
            float ov = __shfl_xor(bv, d);
            int oi = __shfl_xor(bi, d);
            bool take = (ov > bv) || (ov == bv && oi < bi);
            bv = take ? ov : bv;
            bi = take ? oi : bi;
        }
        if (lane == (bi >> 5)) mask |= 1u << (bi & 31);
        if (lane == 0) orow[it] = bi;
    }
}

// ----------------------------------------------------- knn fallback ---------
// Old fused distances + top-32 (used only when ws_size can't hold D').
__global__ __launch_bounds__(256) void knn_kernel(
    const float* __restrict__ x, const float* __restrict__ xx,
    int* __restrict__ idx)
{
    __shared__ float Bs[64][65];
    __shared__ float As[4][65];
    __shared__ float xxs[2048];
    const int t = threadIdx.x, w = t >> 6, lane = t & 63;
    const int b = blockIdx.x >> 9;
    const int r0 = (blockIdx.x & 511) * 4;
    { int row = t >> 6, c = t & 63;
      As[row][c] = x[((size_t)b * 64 + c) * 2048 + r0 + row]; }
    for (int i = 0; i < 8; ++i) { int e = t + 256 * i; xxs[e] = xx[b * 2048 + e]; }
    const float xxr = xx[b * 2048 + r0 + w];
    float v[32];
    for (int jt = 0; jt < 32; ++jt) {
        __syncthreads();
        for (int i = 0; i < 16; ++i) {
            int e = t + 256 * i, c = e >> 6, p = e & 63;
            Bs[p][c] = x[((size_t)b * 64 + c) * 2048 + jt * 64 + p];
        }
        __syncthreads();
        float acc = 0.f;
#pragma unroll
        for (int c = 0; c < 64; ++c) acc += As[w][c] * Bs[lane][c];
        v[jt] = 2.f * acc - xxr - xxs[jt * 64 + lane];
    }
    unsigned mask = 0u;
    int* orow = idx + ((size_t)(b * 2048 + r0 + w)) * 32;
    for (int it = 0; it < 32; ++it) {
        float bv = -INFINITY; int bj = 0;
#pragma unroll
        for (int j = 0; j < 32; ++j) {
            bool ok = !((mask >> j) & 1u) && (v[j] > bv);
            bv = ok ? v[j] : bv;
            bj = ok ? j : bj;
        }
        int bi = bj * 64 + lane;
#pragma unroll
        for (int d = 1; d < 64; d <<= 1) {
            float ov = __shfl_xor(bv, d);
            int oi = __shfl_xor(bi, d);
            bool take = (ov > bv) || (ov == bv && oi < bi);
            bv = take ? ov : bv;
            bi = take ? oi : bi;
        }
        if (lane == (bi & 63)) mask |= 1u << (bi >> 6);
        if (lane == 0) orow[it] = bi;
    }
}

// ---------------------------------------------------------------- attn ------
// Per point: q = (Wq@x_n)/sqrt(8) on the fly; gather 32 neighbor K/V rows;
// energy = q.K[nbr] (the -q.K[n] term is softmax-invariant); serial softmax;
// out = sum a*V[nbr] - V[n] (sum a = 1). A1 = x + out, fp32 point-major.
__global__ __launch_bounds__(256) void attn_kernel(
    const float* __restrict__ x, const float* __restrict__ Wq,
    const float* __restrict__ KT, const float* __restrict__ VT,
    const int* __restrict__ idx, float* __restrict__ A1)
{
    __shared__ float wq[64][65];
    __shared__ int idxs[32];
    __shared__ float xq[64];
    __shared__ float qs[64];
    __shared__ float Kn[32][66], Vn[32][66];
    __shared__ float es[256], av[256];
    const int t = threadIdx.x;
    const int b = blockIdx.x >> 11;
    const int n = blockIdx.x & 2047;
    const size_t pbase = ((size_t)(b * 2048 + n)) * 64;
    if (t < 32) idxs[t] = idx[((size_t)(b * 2048 + n)) * 32 + t] & 2047;  // clamp
    else if (t < 96) xq[t - 32] = x[((size_t)b * 64 + (t - 32)) * 2048 + n];
    for (int i = 0; i < 16; ++i) {
        int e = t + 256 * i;
        wq[e >> 6][e & 63] = Wq[e];
    }
    __syncthreads();
    {   // gather K/V neighbor rows
        int j = t >> 3, c0 = (t & 7) * 8;
        size_t nb = ((size_t)(b * 2048 + idxs[j])) * 64 + c0;
        float4 ka = *reinterpret_cast<const float4*>(KT + nb);
        float4 kb = *reinterpret_cast<const float4*>(KT + nb + 4);
        float4 va = *reinterpret_cast<const float4*>(VT + nb);
        float4 vb = *reinterpret_cast<const float4*>(VT + nb + 4);
        Kn[j][c0 + 0] = ka.x; Kn[j][c0 + 1] = ka.y; Kn[j][c0 + 2] = ka.z; Kn[j][c0 + 3] = ka.w;
        Kn[j][c0 + 4] = kb.x; Kn[j][c0 + 5] = kb.y; Kn[j][c0 + 6] = kb.z; Kn[j][c0 + 7] = kb.w;
        Vn[j][c0 + 0] = va.x; Vn[j][c0 + 1] = va.y; Vn[j][c0 + 2] = va.z; Vn[j][c0 + 3] = va.w;
        Vn[j][c0 + 4] = vb.x; Vn[j][c0 + 5] = vb.y; Vn[j][c0 + 6] = vb.z; Vn[j][c0 + 7] = vb.w;
    }
    if (t < 64) {  // q = (Wq@x)/sqrt(8)
        float a = 0.f;
#pragma unroll
        for (int c = 0; c < 64; ++c) a += wq[t][c] * xq[c];
        qs[t] = a * 0.35355339059327379f;
    }
    __syncthreads();
    {
        int h = t >> 5, j = t & 31;
        float e = 0.f;
#pragma unroll
        for (int d = 0; d < 8; ++d) e += qs[h * 8 + d] * Kn[j][h * 8 + d];
        es[h * 32 + j] = e;
    }
    __syncthreads();
    if (t < 8) {  // serial per-head softmax (denominator >= 1)
        float mx = -INFINITY;
#pragma unroll
        for (int j = 0; j < 32; ++j) mx = fmaxf(mx, es[t * 32 + j]);
        float pv[32], s = 0.f;
#pragma unroll
        for (int j = 0; j < 32; ++j) { pv[j] = __expf(es[t * 32 + j] - mx); s += pv[j]; }
        float inv = 1.f / s;
#pragma unroll
        for (int j = 0; j < 32; ++j) av[t * 32 + j] = pv[j] * inv;
    }
    __syncthreads();
    if (t < 64) {
        int h = t >> 3;
        float acc = 0.f;
#pragma unroll
        for (int j = 0; j < 32; ++j) acc += av[h * 32 + j] * Vn[j][t];
        A1[pbase + t] = acc - VT[pbase + t] + xq[t];
    }
}

// ------------------------------------------------------------- BN stats -----
__global__ __launch_bounds__(256) void bn_partial_kernel(
    const float* __restrict__ Y, float* __restrict__ psum, float* __restrict__ psq)
{
    __shared__ float rs[4][64], rq[4][64];
    const int t = threadIdx.x;
    const int c = t & 63, pg = t >> 6;
    const int b = blockIdx.x >> 3;
    const int n0 = (blockIdx.x & 7) * 256;
    float s = 0.f, q = 0.f;
    for (int k = 0; k < 64; ++k) {
        float v = Y[((size_t)(b * 2048 + n0 + pg * 64 + k)) * 64 + c];
        s += v; q += v * v;
    }
    rs[pg][c] = s; rq[pg][c] = q;
    __syncthreads();
    if (t < 64) {
        psum[blockIdx.x * 64 + t] = rs[0][t] + rs[1][t] + rs[2][t] + rs[3][t];
        psq[blockIdx.x * 64 + t]  = rq[0][t] + rq[1][t] + rq[2][t] + rq[3][t];
    }
}

__global__ void bn_final_kernel(
    const float* __restrict__ psum, const float* __restrict__ psq,
    const float* __restrict__ gamma, const float* __restrict__ beta,
    float* __restrict__ sc, float* __restrict__ sh)
{
    int c = threadIdx.x;  // 64 threads
    float s = 0.f, q = 0.f;
    for (int i = 0; i < 64; ++i) { s += psum[i * 64 + c]; q += psq[i * 64 + c]; }
    float mean = s * (1.f / 16384.f);
    float var = q * (1.f / 16384.f) - mean * mean;
    float g = gamma[c] * rsqrtf(var + 1e-5f);
    sc[c] = g;
    sh[c] = beta[c] - mean * g;
}

// ------------------------------------------------------------ FFN fused -----
// Per 64-point tile: x1 = BN1(A1) -> h = leaky(W1@x1) (LDS) -> P2 = x1 + W2@h.
__global__ __launch_bounds__(256) void ffn_kernel(
    const float* __restrict__ A1, const float* __restrict__ W1,
    const float* __restrict__ W2, const float* __restrict__ s1,
    const float* __restrict__ t1, float* __restrict__ P2)
{
    __shared__ float W1s[8192];
    __shared__ float W2s[8192];
    __shared__ float xs[64][65];
    __shared__ float hs[64][129];
    __shared__ float sts[64], stt[64];
    const int t = threadIdx.x;
    const int b = blockIdx.x >> 5;
    const int n0 = (blockIdx.x & 31) * 64;
    if (t < 64) { sts[t] = s1[t]; stt[t] = t1[t]; }
    for (int i = 0; i < 32; ++i) {
        int e = t + 256 * i;
        W1s[e] = W1[e];
        W2s[e] = W2[e];
    }
    __syncthreads();
    for (int i = 0; i < 16; ++i) {
        int e = t + 256 * i, p = e >> 6, c = e & 63;
        xs[p][c] = A1[((size_t)(b * 2048 + n0 + p)) * 64 + c] * sts[c] + stt[c];
    }
    __syncthreads();
    const int p = t & 63, g = t >> 6;
    {   // h: 32 channels per thread
        float xv[64];
#pragma unroll
        for (int c = 0; c < 64; ++c) xv[c] = xs[p][c];
        for (int u = 0; u < 32; ++u) {
            int j = g * 32 + u;
            float acc = 0.f;
#pragma unroll
            for (int c = 0; c < 64; ++c) acc += W1s[j * 64 + c] * xv[c];
            hs[p][j] = (acc > 0.f) ? acc : 0.2f * acc;  // LeakyReLU 0.2
        }
    }
    __syncthreads();
    {   // P2: 16 channels per thread
        float hv[128];
#pragma unroll
        for (int j = 0; j < 128; ++j) hv[j] = hs[p][j];
        const size_t pbase = ((size_t)(b * 2048 + n0 + p)) * 64 + g * 16;
        float o4[16];
#pragma unroll
        for (int oi = 0; oi < 16; ++oi) {
            int o = g * 16 + oi;
            float a = xs[p][o];  // residual x1
#pragma unroll
            for (int j = 0; j < 128; ++j) a += W2s[o * 128 + j] * hv[j];
            o4[oi] = a;
        }
#pragma unroll
        for (int q = 0; q < 4; ++q)
            *reinterpret_cast<float4*>(P2 + pbase + q * 4) =
                make_float4(o4[q * 4], o4[q * 4 + 1], o4[q * 4 + 2], o4[q * 4 + 3]);
    }
}

// ---------------------------------------------------------------- final -----
// out = BN2(P2), fp32, layout (B, C, N).
__global__ __launch_bounds__(256) void final_kernel(
    const float* __restrict__ P2, const float* __restrict__ s2,
    const float* __restrict__ t2, float* __restrict__ out)
{
    __shared__ float ts[64][65];
    __shared__ float sts[64], stt[64];
    const int t = threadIdx.x;
    const int b = blockIdx.x >> 5;
    const int n0 = (blockIdx.x & 31) * 64;
    if (t < 64) { sts[t] = s2[t]; stt[t] = t2[t]; }
    __syncthreads();
    for (int i = 0; i < 16; ++i) {
        int e = t + 256 * i, p = e >> 6, c = e & 63;
        ts[p][c] = P2[((size_t)(b * 2048 + n0 + p)) * 64 + c] * sts[c] + stt[c];
    }
    __syncthreads();
    const int c = t >> 2, p0 = (t & 3) * 16;
    float* dst = out + ((size_t)(b * 64 + c)) * 2048 + n0 + p0;
#pragma unroll
    for (int q = 0; q < 4; ++q)
        *reinterpret_cast<float4*>(dst + q * 4) =
            make_float4(ts[p0 + q * 4 + 0][c], ts[p0 + q * 4 + 1][c],
                        ts[p0 + q * 4 + 2][c], ts[p0 + q * 4 + 3][c]);
}

// ------------------------------------------------------- safe fallback ------
__global__ __launch_bounds__(256) void zero_kernel(float* __restrict__ out)
{
    reinterpret_cast<float4*>(out)[blockIdx.x * 256 + threadIdx.x] =
        make_float4(0.f, 0.f, 0.f, 0.f);  // 1024*256*16B = 4 MiB
}

// ---------------------------------------------------------------- launch ----
extern "C" void kernel_launch(void* const* d_in, const int* in_sizes, int n_in,
                              void* d_out, int out_size, void* d_ws, size_t ws_size,
                              hipStream_t stream)
{
    const float* x  = (const float*)d_in[0];
    const float* Wq = (const float*)d_in[1];
    const float* Wk = (const float*)d_in[2];
    const float* Wv = (const float*)d_in[3];
    const float* W1 = (const float*)d_in[4];
    const float* W2 = (const float*)d_in[5];
    const float* g1 = (const float*)d_in[6];
    const float* b1 = (const float*)d_in[7];
    const float* g2 = (const float*)d_in[8];
    const float* b2 = (const float*)d_in[9];
    float* out = (float*)d_out;
    (void)in_sizes; (void)n_in; (void)out_size;

    char* ws = (char*)d_ws;
    const size_t off_xx  = 0;                   // 64 KiB
    const size_t off_KT  = 65536;               // 4 MiB fp32 (P2 overlays after attn)
    const size_t off_VT  = off_KT  + 4194304;   // 4 MiB
    const size_t off_idx = off_VT  + 4194304;   // 2 MiB int
    const size_t off_A1  = off_idx + 2097152;   // 4 MiB fp32
    const size_t off_ps1 = off_A1  + 4194304;
    const size_t off_pq1 = off_ps1 + 16384;
    const size_t off_ps2 = off_pq1 + 16384;
    const size_t off_pq2 = off_ps2 + 16384;
    const size_t off_s1  = off_pq2 + 16384;
    const size_t off_t1  = off_s1 + 256;
    const size_t off_s2  = off_t1 + 256;
    const size_t off_t2  = off_s2 + 256;
    const size_t REQ_OLD = off_t2 + 256;        // ~14.1 MiB
    const size_t off_Dp  = 14815232;            // REQ_OLD rounded to 4 KiB
    const size_t DP_SZ   = (size_t)8 * 2048 * 2048 * 4;  // 128 MiB
    const size_t REQ_FAST = off_Dp + DP_SZ;     // ~142.2 MiB

    if (ws_size < REQ_OLD) {  // constant per capture: safe fail
        zero_kernel<<<1024, 256, 0, stream>>>(out);
        return;
    }

    float* xx = (float*)(ws + off_xx);
    float* KT = (float*)(ws + off_KT);
    float* VT = (float*)(ws + off_VT);
    int* idx  = (int*)(ws + off_idx);
    float* A1 = (float*)(ws + off_A1);
    float* P2 = KT;  // KT dead after attn
    float* ps1 = (float*)(ws + off_ps1); float* pq1 = (float*)(ws + off_pq1);
    float* ps2 = (float*)(ws + off_ps2); float* pq2 = (float*)(ws + off_pq2);
    float* s1 = (float*)(ws + off_s1); float* t1 = (float*)(ws + off_t1);
    float* s2 = (float*)(ws + off_s2); float* t2 = (float*)(ws + off_t2);
    float* Dp = (float*)(ws + off_Dp);

    prep_kernel<<<512, 256, 0, stream>>>(x, Wk, Wv, xx, KT, VT);
    if (ws_size >= REQ_FAST) {
        gemm_kernel<<<2048, 256, 0, stream>>>(x, xx, Dp);
        select_kernel<<<4096, 256, 0, stream>>>(Dp, idx);
    } else {
        knn_kernel<<<4096, 256, 0, stream>>>(x, xx, idx);
    }
    attn_kernel<<<16384, 256, 0, stream>>>(x, Wq, KT, VT, idx, A1);
    bn_partial_kernel<<<64, 256, 0, stream>>>(A1, ps1, pq1);
    bn_final_kernel<<<1, 64, 0, stream>>>(ps1, pq1, g1, b1, s1, t1);
    ffn_kernel<<<256, 256, 0, stream>>>(A1, W1, W2, s1, t1, P2);
    bn_partial_kernel<<<64, 256, 0, stream>>>(P2, ps2, pq2);
    bn_final_kernel<<<1, 64, 0, stream>>>(ps2, pq2, g2, b2, s2, t2);
    final_kernel<<<256, 256, 0, stream>>>(P2, s2, t2, out);
}